// Round 14
// baseline (89.128 us; speedup 1.0000x reference)
//
#include <hip/hip_runtime.h>
#include <hip/hip_bf16.h>
#include <hip/hip_fp16.h>

#define ALPHA 0.2f
#define LOG2E 1.44269504088896340736f
constexpr int N = 2048;
constexpr int NW = N / 64;     // 32 mask words per row

typedef __attribute__((ext_vector_type(8))) short short8v;  // bf16 bits x8
typedef __attribute__((ext_vector_type(4))) float f32x4;

__device__ inline unsigned short bf16_rne(float f) {
  unsigned u = __float_as_uint(f);
  return (unsigned short)((u + 0x7fffu + ((u >> 16) & 1u)) >> 16);
}

// packed fp16 ReLU via v_pk_max_f16 (avoids __hmax2 fp16/bf16 overload ambiguity)
__device__ inline __half2 relu_h2(__half2 a) {
  unsigned ua = *(unsigned*)&a, ur;
  asm("v_pk_max_f16 %0, %1, 0" : "=v"(ur) : "v"(ua));
  return *(__half2*)&ur;
}

// ---- Fragment-packed layouts (wave-contiguous 1KB chunks; lane = kgrp*16+il) ----
// wtp[head][otile(4)][ks(K/32)][lane(64)][e(8)]   (A of proj1)
// xp  [ntile(N/16)][ks(K/32)][lane(64)][e(8)]     (B of proj1)
// hTp [head][qchunk(N/32)][ff(4)][lane(64)][e(8)] (B of agg)

// ---------------- prep (slim): pack adj bitmask + W1 packed-transpose ----------------
__global__ void __launch_bounds__(512) prep_kernel(
    const int* __restrict__ adj, const float* __restrict__ gatW1,
    unsigned long long* __restrict__ mask,
    unsigned short* __restrict__ wt1hi, unsigned short* __restrict__ wt1lo) {
  const int t = threadIdx.x, b = blockIdx.x;
  {  // pack adjacency: 512 blocks x 8 waves x 16 words
    int gwave = b * 8 + (t >> 6), lane = t & 63;
#pragma unroll
    for (int i = 0; i < 16; i++) {
      int word = gwave * 16 + i;
      unsigned long long m = __ballot(adj[(size_t)word * 64 + lane] != 0);
      if (lane == 0) mask[word] = m;
    }
  }
  {  // W1 packed-transpose + hi/lo split (65536 elements)
    int gtid = b * 512 + t;
    if (gtid < 65536) {
      int head = gtid >> 14, idx = gtid & 16383;
      int o = idx >> 8, k = idx & 255;
      float v = gatW1[((size_t)head * 256 + k) * 64 + o];
      unsigned short hb = bf16_rne(v);
      size_t oi = (((((size_t)head * 4 + (o >> 4)) * 8 + (k >> 5)) * 4 + ((k & 31) >> 3)) * 16 + (o & 15)) * 8 + (k & 7);
      wt1hi[oi] = hb;
      wt1lo[oi] = bf16_rne(v - __uint_as_float((unsigned)hb << 16));
    }
  }
}

// ---------------- proj0 fused: encoder (in-block) + W0 LDS stage + MFMA ----------------
// grid (N/16, H), block 256 = 4 waves; wave = o-strip. Writes hTp + s1/s2 (log2e) + pm1.
__global__ void __launch_bounds__(256, 4)
proj0_fused_kernel(const float* __restrict__ nf,
                   const float* __restrict__ encW1, const float* __restrict__ encb1,
                   const float* __restrict__ encW2, const float* __restrict__ encb2,
                   const float* __restrict__ gatW0, const float* __restrict__ avec,
                   unsigned short* __restrict__ hT, float* __restrict__ s1, float* __restrict__ s2,
                   float* __restrict__ pm1) {
  const int head = blockIdx.y;
  const int n0 = blockIdx.x * 16;
  const int t = threadIdx.x;
  __shared__ float nfs[16][10];
  __shared__ float x1s[4][65];
  __shared__ float preds[4][4][64];
  __shared__ float xs[16][65];   // encoder output (16 nodes x 64 feat)
  __shared__ float ws0[64][65];  // W0 head slice [k][o], padded
  // --- stage W0 head slice (coalesced over o) ---
  for (int idx = t; idx < 4096; idx += 256) {
    ws0[idx >> 6][idx & 63] = gatW0[(size_t)head * 4096 + idx];
  }
  if (t < 160) nfs[t / 10][t % 10] = nf[(size_t)n0 * 10 + t];
  __syncthreads();
  // --- encoder: 4 batches of 4 nodes ---
  const int j = t >> 6, o = t & 63;
  for (int batch = 0; batch < 4; batch++) {
    float acc = encb1[o];
#pragma unroll
    for (int k = 0; k < 10; k++) acc = fmaf(nfs[batch * 4 + j][k], encW1[k * 64 + o], acc);
    x1s[j][o] = fmaxf(acc, 0.f);
    __syncthreads();
    {
      const int kq = j;
      float pp0 = 0, pp1 = 0, pp2 = 0, pp3 = 0;
#pragma unroll
      for (int kk = 0; kk < 16; kk++) {
        int k = kq * 16 + kk;
        float wv = encW2[k * 64 + o];
        pp0 = fmaf(x1s[0][k], wv, pp0);
        pp1 = fmaf(x1s[1][k], wv, pp1);
        pp2 = fmaf(x1s[2][k], wv, pp2);
        pp3 = fmaf(x1s[3][k], wv, pp3);
      }
      preds[kq][0][o] = pp0; preds[kq][1][o] = pp1;
      preds[kq][2][o] = pp2; preds[kq][3][o] = pp3;
    }
    __syncthreads();
    xs[batch * 4 + j][o] = encb2[o] + preds[0][j][o] + preds[1][j][o] +
                           preds[2][j][o] + preds[3][j][o];
    __syncthreads();
  }
  // --- MFMA phase ---
  const int wave = t >> 6, lane = t & 63;
  const int il = lane & 15, kgrp = lane >> 4;
  const int o0 = wave * 16;
  f32x4 acc = {0, 0, 0, 0};
#pragma unroll
  for (int ks = 0; ks < 2; ks++) {
    const int kbase = ks * 32 + kgrp * 8;
    short8v ah, al, bh;
#pragma unroll
    for (int e = 0; e < 8; e++) {
      float wv = ws0[kbase + e][o0 + il];
      unsigned short hb = bf16_rne(wv);
      ah[e] = (short)hb;
      al[e] = (short)bf16_rne(wv - __uint_as_float((unsigned)hb << 16));
      bh[e] = (short)bf16_rne(xs[il][kbase + e]);
    }
    acc = __builtin_amdgcn_mfma_f32_16x16x32_bf16(ah, bh, acc, 0, 0, 0);
    acc = __builtin_amdgcn_mfma_f32_16x16x32_bf16(al, bh, acc, 0, 0, 0);
  }
  // D: o = o0 + kgrp*4 + r (row), n = n0 + il (col). Write hTp layout.
  const int n = n0 + il;
  const size_t cbase = (((size_t)head * (N / 32) + (n >> 5)) * 4 + wave) * 512;
  const int sub = ((n & 31) >> 3) * 16;
  const int eoff = n & 7;
  float p1 = 0.f, p2 = 0.f;
#pragma unroll
  for (int r = 0; r < 4; r++) {
    const int oo = o0 + kgrp * 4 + r;
    hT[cbase + (size_t)(sub + kgrp * 4 + r) * 8 + eoff] = bf16_rne(acc[r]);
    p1 = fmaf(acc[r], avec[head * 128 + oo], p1);
    p2 = fmaf(acc[r], avec[head * 128 + 64 + oo], p2);
  }
  p1 += __shfl_xor(p1, 16); p1 += __shfl_xor(p1, 32);
  p2 += __shfl_xor(p2, 16); p2 += __shfl_xor(p2, 32);
  __shared__ float s1p[4][16], s2p[4][16];
  if (kgrp == 0) { s1p[wave][il] = p1; s2p[wave][il] = p2; }
  __syncthreads();
  if (t < 16) {
    int nn = n0 + t;
    float v1 = (s1p[0][t] + s1p[1][t] + s1p[2][t] + s1p[3][t]) * LOG2E;
    float v2 = (s2p[0][t] + s2p[1][t] + s2p[2][t] + s2p[3][t]) * LOG2E;
    s1[head * N + nn] = v1;
    s2[head * N + nn] = v2;
    float m1 = v1;
#pragma unroll
    for (int s = 1; s < 16; s <<= 1) m1 = fmaxf(m1, __shfl_xor(m1, s));
    if (t == 0) pm1[head * 128 + blockIdx.x] = m1;
  }
}

// ---------------- proj1: MFMA (fragment-packed operands, 2-term hi/lo) ----------------
__global__ void __launch_bounds__(256, 4)
proj_mfma_kernel(const unsigned short* __restrict__ xhi,
                 const unsigned short* __restrict__ wthi, const unsigned short* __restrict__ wtlo,
                 const float* __restrict__ avec,
                 unsigned short* __restrict__ hT, float* __restrict__ s1, float* __restrict__ s2,
                 float* __restrict__ pm1) {
  constexpr int KS = 8;  // K=256
  const int head = blockIdx.y;
  const int n0 = blockIdx.x * 16;
  const int wave = threadIdx.x >> 6, lane = threadIdx.x & 63;
  const int il = lane & 15, kgrp = lane >> 4;
  const int o0 = wave * 16;
  const unsigned short* __restrict__ Ah = wthi + ((size_t)(head * 4 + wave) * KS) * 512 + lane * 8;
  const unsigned short* __restrict__ Al = wtlo + ((size_t)(head * 4 + wave) * KS) * 512 + lane * 8;
  const unsigned short* __restrict__ Bh = xhi + ((size_t)blockIdx.x * KS) * 512 + lane * 8;
  f32x4 acc = {0, 0, 0, 0};
#pragma unroll
  for (int ks = 0; ks < KS; ks++) {
    short8v ah = *(const short8v*)(Ah + ks * 512);
    short8v al = *(const short8v*)(Al + ks * 512);
    short8v bh = *(const short8v*)(Bh + ks * 512);
    acc = __builtin_amdgcn_mfma_f32_16x16x32_bf16(ah, bh, acc, 0, 0, 0);
    acc = __builtin_amdgcn_mfma_f32_16x16x32_bf16(al, bh, acc, 0, 0, 0);
  }
  const int n = n0 + il;
  const size_t cbase = (((size_t)head * (N / 32) + (n >> 5)) * 4 + wave) * 512;
  const int sub = ((n & 31) >> 3) * 16;
  const int eoff = n & 7;
  float p1 = 0.f, p2 = 0.f;
#pragma unroll
  for (int r = 0; r < 4; r++) {
    const int o = o0 + kgrp * 4 + r;
    hT[cbase + (size_t)(sub + kgrp * 4 + r) * 8 + eoff] = bf16_rne(acc[r]);
    p1 = fmaf(acc[r], avec[head * 128 + o], p1);
    p2 = fmaf(acc[r], avec[head * 128 + 64 + o], p2);
  }
  p1 += __shfl_xor(p1, 16); p1 += __shfl_xor(p1, 32);
  p2 += __shfl_xor(p2, 16); p2 += __shfl_xor(p2, 32);
  __shared__ float s1p[4][16], s2p[4][16];
  if (kgrp == 0) { s1p[wave][il] = p1; s2p[wave][il] = p2; }
  __syncthreads();
  if (threadIdx.x < 16) {
    int nn = n0 + threadIdx.x;
    float v1 = (s1p[0][threadIdx.x] + s1p[1][threadIdx.x] + s1p[2][threadIdx.x] + s1p[3][threadIdx.x]) * LOG2E;
    float v2 = (s2p[0][threadIdx.x] + s2p[1][threadIdx.x] + s2p[2][threadIdx.x] + s2p[3][threadIdx.x]) * LOG2E;
    s1[head * N + nn] = v1;
    s2[head * N + nn] = v2;
    float m1 = v1;
#pragma unroll
    for (int s = 1; s < 16; s <<= 1) m1 = fmaxf(m1, __shfl_xor(m1, s));
    if (threadIdx.x == 0) pm1[head * 128 + blockIdx.x] = m1;
  }
}

// ---------------- fused MFMA aggregation + denom + normalize + ELU + concat ----------------
template <bool WF32, bool WBF>
__global__ void __launch_bounds__(512, 4)
agg_fused_kernel(const unsigned short* __restrict__ hTu,
                 const float* __restrict__ s1, const float* __restrict__ s2,
                 const float* __restrict__ pm1,
                 const unsigned long long* __restrict__ mask,
                 float* __restrict__ xout, unsigned short* __restrict__ xohi) {
  const int head = blockIdx.y;
  const int p0 = blockIdx.x * 16;
  const int wave = threadIdx.x >> 6, lane = threadIdx.x & 63;
  const int col = lane & 15, kgrp = lane >> 4;
  const int p = p0 + col;
  const float s2pv = s2[head * N + p];
  float sm = fmaxf(pm1[head * 128 + lane], pm1[head * 128 + 64 + lane]);
#pragma unroll
  for (int s = 1; s < 64; s <<= 1) sm = fmaxf(sm, __shfl_xor(sm, s));
  const float mraw = sm + s2pv;
  const float mp = fmaxf(mraw, ALPHA * mraw);
  const float c1 = s2pv - mp;
  const float c2 = ALPHA * s2pv - mp;
  const float* __restrict__ s1h = s1 + head * N;
  const int qbase = wave * 256;
  const unsigned long long* __restrict__ mr = mask + (size_t)p * NW + (qbase >> 6);
  unsigned long long mw0 = mr[0], mw1 = mr[1], mw2 = mr[2], mw3 = mr[3];
  const unsigned short* __restrict__ bbase =
      hTu + (((size_t)head * (N / 32) + wave * 8) * 4) * 512 + lane * 8;

  f32x4 acc[4] = {{0,0,0,0},{0,0,0,0},{0,0,0,0},{0,0,0,0}};
  float wsum = 0.f;
#pragma unroll
  for (int ks = 0; ks < 8; ks++) {
    const int qa = qbase + ks * 32 + kgrp * 8;
    float4 s1v0 = *(const float4*)(s1h + qa);
    float4 s1v1 = *(const float4*)(s1h + qa + 4);
    unsigned long long mwsel = (ks < 2) ? mw0 : (ks < 4) ? mw1 : (ks < 6) ? mw2 : mw3;
    unsigned b8 = (unsigned)((mwsel >> ((ks & 1) * 32 + kgrp * 8)) & 0xFFull);
    float sv[8] = {s1v0.x, s1v0.y, s1v0.z, s1v0.w, s1v1.x, s1v1.y, s1v1.z, s1v1.w};
    float w[8];
#pragma unroll
    for (int e = 0; e < 8; e++) {
      float lr = fmaxf(sv[e] + c1, fmaf(sv[e], ALPHA, c2));
      float ww = exp2f(lr);
      ww = ((b8 >> e) & 1u) ? ww : 0.f;
      wsum += ww;
      w[e] = ww;
    }
    union { short8v s; unsigned u[4]; } av;
#pragma unroll
    for (int e2 = 0; e2 < 4; e2++)
      asm("v_cvt_pk_bf16_f32 %0, %1, %2" : "=v"(av.u[e2]) : "v"(w[2 * e2]), "v"(w[2 * e2 + 1]));
#pragma unroll
    for (int ff = 0; ff < 4; ff++) {
      short8v b_hi = *(const short8v*)(bbase + ((size_t)ks * 4 + ff) * 512);
      acc[ff] = __builtin_amdgcn_mfma_f32_16x16x32_bf16(av.s, b_hi, acc[ff], 0, 0, 0);
    }
  }
  wsum += __shfl_xor(wsum, 16);
  wsum += __shfl_xor(wsum, 32);

  __shared__ float red[8][16][65];
  __shared__ float wred[8][16];
#pragma unroll
  for (int ff = 0; ff < 4; ff++)
#pragma unroll
    for (int r = 0; r < 4; r++)
      red[wave][kgrp * 4 + r][ff * 16 + col] = acc[ff][r];
  if (lane < 16) wred[wave][lane] = wsum;
  __syncthreads();
#pragma unroll
  for (int rep = 0; rep < 2; rep++) {
    int idx = threadIdx.x + rep * 512;
    int pl = idx >> 6, f = idx & 63;
    float num = 0.f, dn = 0.f;
#pragma unroll
    for (int w8 = 0; w8 < 8; w8++) { num += red[w8][pl][f]; dn += wred[w8][pl]; }
    float v = num / dn;
    v = v > 0.f ? v : (__expf(v) - 1.f);
    if (WF32) xout[(size_t)(p0 + pl) * 256 + head * 64 + f] = v;
    if (WBF) {
      size_t oi = ((((size_t)blockIdx.x * 8 + head * 2 + (f >> 5)) * 4 + ((f & 31) >> 3)) * 16 + pl) * 8 + (f & 7);
      xohi[oi] = bf16_rne(v);
    }
  }
}

// ---------------- layer-2 projection (F_out=3), 4 nodes/block, h2 stride-4 ----------------
__global__ void h3_kernel(const float* __restrict__ x, const float* __restrict__ W,
                          const float* __restrict__ a, float* __restrict__ h2,
                          float* __restrict__ s1, float* __restrict__ s2,
                          float* __restrict__ pm1h3) {
  const int n0 = blockIdx.x * 4;
  const int head = threadIdx.x >> 6, o = threadIdx.x & 63;
  __shared__ float xr[4][256];
  for (int k = threadIdx.x; k < 1024; k += 256) xr[k >> 8][k & 255] = x[(size_t)n0 * 256 + k];
  __syncthreads();
  const float* __restrict__ Wh = W + (size_t)head * 256 * 3;
  float m1 = -3.4e38f;
#pragma unroll
  for (int jj = 0; jj < 4; jj++) {
    float a0 = 0.f, a1 = 0.f, a2 = 0.f;
#pragma unroll
    for (int i = 0; i < 4; i++) {
      int k = o + 64 * i;
      float xv = xr[jj][k];
      a0 = fmaf(xv, Wh[k * 3 + 0], a0);
      a1 = fmaf(xv, Wh[k * 3 + 1], a1);
      a2 = fmaf(xv, Wh[k * 3 + 2], a2);
    }
    for (int s = 32; s; s >>= 1) {
      a0 += __shfl_xor(a0, s); a1 += __shfl_xor(a1, s); a2 += __shfl_xor(a2, s);
    }
    float p1 = (a0 * a[head * 6 + 0] + a1 * a[head * 6 + 1] + a2 * a[head * 6 + 2]) * LOG2E;
    float p2 = (a0 * a[head * 6 + 3] + a1 * a[head * 6 + 4] + a2 * a[head * 6 + 5]) * LOG2E;
    m1 = fmaxf(m1, p1);
    if (o == 0) {
      float* hq = h2 + ((size_t)head * N + n0 + jj) * 4;
      hq[0] = a0; hq[1] = a1; hq[2] = a2; hq[3] = 0.f;
      s1[head * N + n0 + jj] = p1;
      s2[head * N + n0 + jj] = p2;
    }
  }
  if (o == 0) pm1h3[head * 512 + blockIdx.x] = m1;
}

// ---------------- layer-2 aggregation, self-normalizing, fused head-mean + ELU -> emb ----------------
__global__ void agg2_kernel(const float* __restrict__ h2, const float* __restrict__ s1,
                            const float* __restrict__ s2, const float* __restrict__ pm1h3,
                            const unsigned long long* __restrict__ mask,
                            float* __restrict__ emb) {
  const int p = blockIdx.x;
  const int head = threadIdx.x >> 6, lane = threadIdx.x & 63;
  const float s2pv = s2[head * N + p];
  float sm = -3.4e38f;
  for (int i = lane; i < 512; i += 64) sm = fmaxf(sm, pm1h3[head * 512 + i]);
#pragma unroll
  for (int s = 1; s < 64; s <<= 1) sm = fmaxf(sm, __shfl_xor(sm, s));
  float mraw = sm + s2pv;
  const float mhv = fmaxf(mraw, ALPHA * mraw);
  const float c1 = s2pv - mhv;
  const float c2 = ALPHA * s2pv - mhv;
  const float* __restrict__ s1h = s1 + head * N;
  float a0 = 0.f, a1 = 0.f, a2 = 0.f, wsum = 0.f;
#pragma unroll 2
  for (int i = 0; i < 32; i++) {
    unsigned long long mwd = mask[(size_t)p * NW + i];
    int q = i * 64 + lane;
    if ((mwd >> lane) & 1ull) {
      float sv = s1h[q];
      float lr = fmaxf(sv + c1, fmaf(sv, ALPHA, c2));
      float w = exp2f(lr);
      float4 hv = *(const float4*)(h2 + ((size_t)head * N + q) * 4);
      a0 = fmaf(w, hv.x, a0);
      a1 = fmaf(w, hv.y, a1);
      a2 = fmaf(w, hv.z, a2);
      wsum += w;
    }
  }
  for (int s = 32; s; s >>= 1) {
    a0 += __shfl_xor(a0, s); a1 += __shfl_xor(a1, s);
    a2 += __shfl_xor(a2, s); wsum += __shfl_xor(wsum, s);
  }
  __shared__ float red[4][4];
  if (lane == 0) { red[head][0] = a0; red[head][1] = a1; red[head][2] = a2; red[head][3] = wsum; }
  __syncthreads();
  if (threadIdx.x < 3) {
    int f = threadIdx.x;
    float v = 0.f;
#pragma unroll
    for (int hh = 0; hh < 4; hh++) v += red[hh][f] / red[hh][3];
    v *= 0.25f;
    v = v > 0.f ? v : (__expf(v) - 1.f);
    emb[p * 3 + f] = v;
  }
}

// ---------------- all-pairs edge classifier (packed fp16 inner) ----------------
__global__ void cls_kernel(const float* __restrict__ emb,
                           const float* __restrict__ W1, const float* __restrict__ b1,
                           const float* __restrict__ W2, const float* __restrict__ b2,
                           float* __restrict__ out) {
  int q = blockIdx.x * 256 + threadIdx.x;
  int p0 = blockIdx.y * 8;
  __shared__ float ep[8][3];
  __shared__ __half2 w1h[96], b1h[32], w2h[32];
  __shared__ float b2s;
  int t = threadIdx.x;
  if (t < 96) w1h[t] = __float2half2_rn(W1[t]);
  else if (t < 128) b1h[t - 96] = __float2half2_rn(b1[t - 96]);
  else if (t < 160) w2h[t - 128] = __float2half2_rn(W2[t - 128]);
  else if (t == 160) b2s = b2[0];
  else if (t >= 192 && t < 216) ((float*)ep)[t - 192] = emb[p0 * 3 + t - 192];
  __syncthreads();
  float e0 = emb[q * 3 + 0], e1 = emb[q * 3 + 1], e2 = emb[q * 3 + 2];
  __half2 d0[4], d1[4], d2[4];
#pragma unroll
  for (int ip = 0; ip < 4; ip++) {
    d0[ip] = __floats2half2_rn(fabsf(ep[2 * ip][0] - e0), fabsf(ep[2 * ip + 1][0] - e0));
    d1[ip] = __floats2half2_rn(fabsf(ep[2 * ip][1] - e1), fabsf(ep[2 * ip + 1][1] - e1));
    d2[ip] = __floats2half2_rn(fabsf(ep[2 * ip][2] - e2), fabsf(ep[2 * ip + 1][2] - e2));
  }
  const __half2 hz = __float2half2_rn(0.f);
  __half2 acc[4] = {hz, hz, hz, hz};
#pragma unroll
  for (int j = 0; j < 32; j++) {
    __half2 c0 = w1h[j], c1 = w1h[32 + j], c2 = w1h[64 + j], bb = b1h[j], w2 = w2h[j];
#pragma unroll
    for (int ip = 0; ip < 4; ip++) {
      __half2 hv = __hfma2(d0[ip], c0, __hfma2(d1[ip], c1, __hfma2(d2[ip], c2, bb)));
      hv = relu_h2(hv);
      acc[ip] = __hfma2(hv, w2, acc[ip]);
    }
  }
#pragma unroll
  for (int ip = 0; ip < 4; ip++) {
    float x0 = __low2float(acc[ip]) + b2s;
    float x1 = __high2float(acc[ip]) + b2s;
    out[(size_t)(p0 + 2 * ip) * N + q] = 1.f / (1.f + __expf(-x0));
    out[(size_t)(p0 + 2 * ip + 1) * N + q] = 1.f / (1.f + __expf(-x1));
  }
}

extern "C" void kernel_launch(void* const* d_in, const int* in_sizes, int n_in,
                              void* d_out, int out_size, void* d_ws, size_t ws_size,
                              hipStream_t stream) {
  const float* nf    = (const float*)d_in[0];
  const int*   adj   = (const int*)d_in[1];
  const float* encW1 = (const float*)d_in[2];
  const float* encb1 = (const float*)d_in[3];
  const float* encW2 = (const float*)d_in[4];
  const float* encb2 = (const float*)d_in[5];
  const float* gatW0 = (const float*)d_in[6];
  const float* gata0 = (const float*)d_in[7];
  const float* gatW1 = (const float*)d_in[8];
  const float* gata1 = (const float*)d_in[9];
  const float* gatW2 = (const float*)d_in[10];
  const float* gata2 = (const float*)d_in[11];
  const float* clsW1 = (const float*)d_in[12];
  const float* clsb1 = (const float*)d_in[13];
  const float* clsW2 = (const float*)d_in[14];
  const float* clsb2 = (const float*)d_in[15];

  float* ws = (float*)d_ws;
  unsigned short* hT   = (unsigned short*)ws;              // 524288 sh = 262144 f
  float* s1   = ws + 262144;                               // 8192
  float* s2   = s1 + 8192;                                 // 8192
  float* pm1  = s2 + 8192;                                 // 512
  float* pm1h3= pm1 + 512;                                 // 2048
  unsigned short* wt1hi= (unsigned short*)(pm1h3 + 2048);  // 32768 f
  unsigned short* wt1lo= wt1hi + 65536;                    // 32768 f
  unsigned short* xAhi = wt1lo + 65536;                    // 262144 f
  float* xB   = (float*)(xAhi + 524288);                   // 524288 f
  float* h2   = xB + 524288;                               // 32768 f (stride-4)
  unsigned long long* mask = (unsigned long long*)(h2 + 32768); // 131072 f

  float* emb = (float*)d_out;
  float* eprob = emb + N * 3;

  prep_kernel<<<dim3(512), dim3(512), 0, stream>>>(adj, gatW1, mask, wt1hi, wt1lo);

  // ---- GAT layer 0 (fused encoder + projection) ----
  proj0_fused_kernel<<<dim3(N / 16, 4), dim3(256), 0, stream>>>(
      nf, encW1, encb1, encW2, encb2, gatW0, gata0, hT, s1, s2, pm1);
  agg_fused_kernel<false, true><<<dim3(N / 16, 4), dim3(512), 0, stream>>>(
      hT, s1, s2, pm1, mask, nullptr, xAhi);

  // ---- GAT layer 1 ----
  proj_mfma_kernel<<<dim3(N / 16, 4), dim3(256), 0, stream>>>(
      xAhi, wt1hi, wt1lo, gata1, hT, s1, s2, pm1);
  agg_fused_kernel<true, false><<<dim3(N / 16, 4), dim3(512), 0, stream>>>(
      hT, s1, s2, pm1, mask, xB, nullptr);

  // ---- GAT layer 2 ----
  h3_kernel<<<dim3(N / 4), dim3(256), 0, stream>>>(xB, gatW2, gata2, h2, s1, s2, pm1h3);
  agg2_kernel<<<dim3(N), dim3(256), 0, stream>>>(h2, s1, s2, pm1h3, mask, emb);

  // ---- classifier ----
  cls_kernel<<<dim3(8, N / 8), dim3(256), 0, stream>>>(emb, clsW1, clsb1, clsW2, clsb2, eprob);
}

// Round 15
// 85.072 us; speedup vs baseline: 1.0477x; 1.0477x over previous
//
#include <hip/hip_runtime.h>
#include <hip/hip_bf16.h>
#include <hip/hip_fp16.h>

#define ALPHA 0.2f
#define LOG2E 1.44269504088896340736f
constexpr int N = 2048;
constexpr int NW = N / 64;     // 32 mask words per row

typedef __attribute__((ext_vector_type(8))) short short8v;  // bf16 bits x8
typedef __attribute__((ext_vector_type(4))) float f32x4;

__device__ inline unsigned short bf16_rne(float f) {
  unsigned u = __float_as_uint(f);
  return (unsigned short)((u + 0x7fffu + ((u >> 16) & 1u)) >> 16);
}

// packed fp16 ReLU via v_pk_max_f16 (avoids __hmax2 fp16/bf16 overload ambiguity)
__device__ inline __half2 relu_h2(__half2 a) {
  unsigned ua = *(unsigned*)&a, ur;
  asm("v_pk_max_f16 %0, %1, 0" : "=v"(ur) : "v"(ua));
  return *(__half2*)&ur;
}

// ---- Fragment-packed layouts (wave-contiguous 1KB chunks; lane = kgrp*16+il) ----
// wtp[head][otile(4)][ks(K/32)][lane(64)][e(8)]   (A of proj: row o = ot*16+il, k = ks*32+(lane>>4)*8+e)
// xp  [ntile(N/16)][ks(K/32)][lane(64)][e(8)]     (B of proj: col n = nt*16+il)
// hTp [head][qchunk(N/32)][ff(4)][lane(64)][e(8)] (B of agg: f = ff*16+(lane&15), q = qc*32+(lane>>4)*8+e)

// ---------------- prep: pack adj + W transpose/split/pack + encoder ----------------
__global__ void __launch_bounds__(512) prep_kernel(
    const float* __restrict__ nf, const int* __restrict__ adj,
    const float* __restrict__ encW1, const float* __restrict__ encb1,
    const float* __restrict__ encW2, const float* __restrict__ encb2,
    const float* __restrict__ gatW0, const float* __restrict__ gatW1,
    unsigned long long* __restrict__ mask,
    unsigned short* __restrict__ wt0hi, unsigned short* __restrict__ wt0lo,
    unsigned short* __restrict__ wt1hi, unsigned short* __restrict__ wt1lo,
    unsigned short* __restrict__ x0hi) {
  const int t = threadIdx.x, b = blockIdx.x;
  {  // pack adjacency: 512 blocks x 8 waves x 16 words
    int gwave = b * 8 + (t >> 6), lane = t & 63;
#pragma unroll
    for (int i = 0; i < 16; i++) {
      int word = gwave * 16 + i;
      unsigned long long m = __ballot(adj[(size_t)word * 64 + lane] != 0);
      if (lane == 0) mask[word] = m;
    }
  }
  {  // W0/W1 packed-transpose + hi/lo split
    int gtid = b * 512 + t;
    if (gtid < 16384) {  // W0: K=64 (KS=2)
      int head = gtid >> 12, idx = gtid & 4095;
      int o = idx >> 6, k = idx & 63;
      float v = gatW0[(head * 64 + k) * 64 + o];
      unsigned short hb = bf16_rne(v);
      size_t oi = (((((size_t)head * 4 + (o >> 4)) * 2 + (k >> 5)) * 4 + ((k & 31) >> 3)) * 16 + (o & 15)) * 8 + (k & 7);
      wt0hi[oi] = hb;
      wt0lo[oi] = bf16_rne(v - __uint_as_float((unsigned)hb << 16));
    }
    if (gtid < 65536) {  // W1: K=256 (KS=8)
      int head = gtid >> 14, idx = gtid & 16383;
      int o = idx >> 8, k = idx & 255;
      float v = gatW1[((size_t)head * 256 + k) * 64 + o];
      unsigned short hb = bf16_rne(v);
      size_t oi = (((((size_t)head * 4 + (o >> 4)) * 8 + (k >> 5)) * 4 + ((k & 31) >> 3)) * 16 + (o & 15)) * 8 + (k & 7);
      wt1hi[oi] = hb;
      wt1lo[oi] = bf16_rne(v - __uint_as_float((unsigned)hb << 16));
    }
  }
  if (b < 256) {  // encoder MLP, 8 nodes/block (two 4-node halves)
    __shared__ float nfs[2][4][10], x1e[2][4][64], pred[2][4][4][64];
    const int half = t >> 8, tl = t & 255;
    const int j = tl >> 6, o = tl & 63;
    const int n0 = b * 8 + half * 4;
    if (tl < 40) nfs[half][tl / 10][tl % 10] = nf[n0 * 10 + tl];
    __syncthreads();
    float acc = encb1[o];
#pragma unroll
    for (int k = 0; k < 10; k++) acc = fmaf(nfs[half][j][k], encW1[k * 64 + o], acc);
    x1e[half][j][o] = fmaxf(acc, 0.f);
    __syncthreads();
    {
      const int kq = j;
      float pp0 = 0, pp1 = 0, pp2 = 0, pp3 = 0;
#pragma unroll
      for (int kk = 0; kk < 16; kk++) {
        int k = kq * 16 + kk;
        float wv = encW2[k * 64 + o];
        pp0 = fmaf(x1e[half][0][k], wv, pp0);
        pp1 = fmaf(x1e[half][1][k], wv, pp1);
        pp2 = fmaf(x1e[half][2][k], wv, pp2);
        pp3 = fmaf(x1e[half][3][k], wv, pp3);
      }
      pred[half][kq][0][o] = pp0; pred[half][kq][1][o] = pp1;
      pred[half][kq][2][o] = pp2; pred[half][kq][3][o] = pp3;
    }
    __syncthreads();
    float v = encb2[o] + pred[half][0][j][o] + pred[half][1][j][o] +
              pred[half][2][j][o] + pred[half][3][j][o];
    const int n = n0 + j;  // node; feature k = o; K=64 -> KS=2
    size_t oi = ((((size_t)(n >> 4) * 2 + (o >> 5)) * 4 + ((o & 31) >> 3)) * 16 + (n & 15)) * 8 + (o & 7);
    x0hi[oi] = bf16_rne(v);
  }
}

// ---------------- MFMA projection (fragment-packed operands, 2-term hi/lo) ----------------
// grid (N/16, H), block 256 = 4 waves; wave = o-strip. Writes hTp + s1/s2 (log2e) + pm1.
template <int K>
__global__ void __launch_bounds__(256, 4)
proj_mfma_kernel(const unsigned short* __restrict__ xhi,
                 const unsigned short* __restrict__ wthi, const unsigned short* __restrict__ wtlo,
                 const float* __restrict__ avec,
                 unsigned short* __restrict__ hT, float* __restrict__ s1, float* __restrict__ s2,
                 float* __restrict__ pm1) {
  constexpr int KS = K / 32;
  const int head = blockIdx.y;
  const int n0 = blockIdx.x * 16;
  const int wave = threadIdx.x >> 6, lane = threadIdx.x & 63;
  const int il = lane & 15, kgrp = lane >> 4;
  const int o0 = wave * 16;
  const unsigned short* __restrict__ Ah = wthi + ((size_t)(head * 4 + wave) * KS) * 512 + lane * 8;
  const unsigned short* __restrict__ Al = wtlo + ((size_t)(head * 4 + wave) * KS) * 512 + lane * 8;
  const unsigned short* __restrict__ Bh = xhi + ((size_t)blockIdx.x * KS) * 512 + lane * 8;
  f32x4 acc = {0, 0, 0, 0};
#pragma unroll
  for (int ks = 0; ks < KS; ks++) {
    short8v ah = *(const short8v*)(Ah + ks * 512);
    short8v al = *(const short8v*)(Al + ks * 512);
    short8v bh = *(const short8v*)(Bh + ks * 512);
    acc = __builtin_amdgcn_mfma_f32_16x16x32_bf16(ah, bh, acc, 0, 0, 0);
    acc = __builtin_amdgcn_mfma_f32_16x16x32_bf16(al, bh, acc, 0, 0, 0);
  }
  // D: o = o0 + kgrp*4 + r (row), n = n0 + il (col). Write hTp layout.
  const int n = n0 + il;
  const size_t cbase = (((size_t)head * (N / 32) + (n >> 5)) * 4 + wave) * 512;
  const int sub = ((n & 31) >> 3) * 16;  // kgrp_agg*16
  const int eoff = n & 7;
  float p1 = 0.f, p2 = 0.f;
#pragma unroll
  for (int r = 0; r < 4; r++) {
    const int o = o0 + kgrp * 4 + r;
    hT[cbase + (size_t)(sub + kgrp * 4 + r) * 8 + eoff] = bf16_rne(acc[r]);
    p1 = fmaf(acc[r], avec[head * 128 + o], p1);
    p2 = fmaf(acc[r], avec[head * 128 + 64 + o], p2);
  }
  p1 += __shfl_xor(p1, 16); p1 += __shfl_xor(p1, 32);
  p2 += __shfl_xor(p2, 16); p2 += __shfl_xor(p2, 32);
  __shared__ float s1p[4][16], s2p[4][16];
  if (kgrp == 0) { s1p[wave][il] = p1; s2p[wave][il] = p2; }
  __syncthreads();
  if (threadIdx.x < 16) {
    int nn = n0 + threadIdx.x;
    float v1 = (s1p[0][threadIdx.x] + s1p[1][threadIdx.x] + s1p[2][threadIdx.x] + s1p[3][threadIdx.x]) * LOG2E;
    float v2 = (s2p[0][threadIdx.x] + s2p[1][threadIdx.x] + s2p[2][threadIdx.x] + s2p[3][threadIdx.x]) * LOG2E;
    s1[head * N + nn] = v1;
    s2[head * N + nn] = v2;
    float m1 = v1;
#pragma unroll
    for (int s = 1; s < 16; s <<= 1) m1 = fmaxf(m1, __shfl_xor(m1, s));
    if (threadIdx.x == 0) pm1[head * 128 + blockIdx.x] = m1;
  }
}

// ---------------- fused MFMA aggregation + denom + normalize + ELU + concat ----------------
// grid (N/16, H), block 512 = 8 waves; wave w = K-chunk of 256 q. Single-MFMA, packed B.
// VALU-trimmed: lrelu-sub fold (c1/c2) + v_cvt_pk_bf16_f32 packing.
template <bool WF32, bool WBF>
__global__ void __launch_bounds__(512, 4)
agg_fused_kernel(const unsigned short* __restrict__ hTu,
                 const float* __restrict__ s1, const float* __restrict__ s2,
                 const float* __restrict__ pm1,
                 const unsigned long long* __restrict__ mask,
                 float* __restrict__ xout, unsigned short* __restrict__ xohi) {
  const int head = blockIdx.y;
  const int p0 = blockIdx.x * 16;
  const int wave = threadIdx.x >> 6, lane = threadIdx.x & 63;
  const int col = lane & 15, kgrp = lane >> 4;
  const int p = p0 + col;
  const float s2pv = s2[head * N + p];
  float sm = fmaxf(pm1[head * 128 + lane], pm1[head * 128 + 64 + lane]);
#pragma unroll
  for (int s = 1; s < 64; s <<= 1) sm = fmaxf(sm, __shfl_xor(sm, s));
  const float mraw = sm + s2pv;
  const float mp = fmaxf(mraw, ALPHA * mraw);
  // fold: lrelu(sv+s2p) - mp = max(sv + c1, ALPHA*sv + c2)
  const float c1 = s2pv - mp;
  const float c2 = ALPHA * s2pv - mp;
  const float* __restrict__ s1h = s1 + head * N;
  const int qbase = wave * 256;
  const unsigned long long* __restrict__ mr = mask + (size_t)p * NW + (qbase >> 6);
  unsigned long long mw0 = mr[0], mw1 = mr[1], mw2 = mr[2], mw3 = mr[3];
  const unsigned short* __restrict__ bbase =
      hTu + (((size_t)head * (N / 32) + wave * 8) * 4) * 512 + lane * 8;

  f32x4 acc[4] = {{0,0,0,0},{0,0,0,0},{0,0,0,0},{0,0,0,0}};
  float wsum = 0.f;
#pragma unroll
  for (int ks = 0; ks < 8; ks++) {
    const int qa = qbase + ks * 32 + kgrp * 8;
    float4 s1v0 = *(const float4*)(s1h + qa);
    float4 s1v1 = *(const float4*)(s1h + qa + 4);
    unsigned long long mwsel = (ks < 2) ? mw0 : (ks < 4) ? mw1 : (ks < 6) ? mw2 : mw3;
    unsigned b8 = (unsigned)((mwsel >> ((ks & 1) * 32 + kgrp * 8)) & 0xFFull);
    float sv[8] = {s1v0.x, s1v0.y, s1v0.z, s1v0.w, s1v1.x, s1v1.y, s1v1.z, s1v1.w};
    float w[8];
#pragma unroll
    for (int e = 0; e < 8; e++) {
      float lr = fmaxf(sv[e] + c1, fmaf(sv[e], ALPHA, c2));
      float ww = exp2f(lr);
      ww = ((b8 >> e) & 1u) ? ww : 0.f;
      wsum += ww;
      w[e] = ww;
    }
    union { short8v s; unsigned u[4]; } av;
#pragma unroll
    for (int e2 = 0; e2 < 4; e2++)
      asm("v_cvt_pk_bf16_f32 %0, %1, %2" : "=v"(av.u[e2]) : "v"(w[2 * e2]), "v"(w[2 * e2 + 1]));
#pragma unroll
    for (int ff = 0; ff < 4; ff++) {
      short8v b_hi = *(const short8v*)(bbase + ((size_t)ks * 4 + ff) * 512);
      acc[ff] = __builtin_amdgcn_mfma_f32_16x16x32_bf16(av.s, b_hi, acc[ff], 0, 0, 0);
    }
  }
  wsum += __shfl_xor(wsum, 16);
  wsum += __shfl_xor(wsum, 32);

  __shared__ float red[8][16][65];
  __shared__ float wred[8][16];
#pragma unroll
  for (int ff = 0; ff < 4; ff++)
#pragma unroll
    for (int r = 0; r < 4; r++)
      red[wave][kgrp * 4 + r][ff * 16 + col] = acc[ff][r];
  if (lane < 16) wred[wave][lane] = wsum;
  __syncthreads();
#pragma unroll
  for (int rep = 0; rep < 2; rep++) {
    int idx = threadIdx.x + rep * 512;
    int pl = idx >> 6, f = idx & 63;
    float num = 0.f, dn = 0.f;
#pragma unroll
    for (int w8 = 0; w8 < 8; w8++) { num += red[w8][pl][f]; dn += wred[w8][pl]; }
    float v = num / dn;
    v = v > 0.f ? v : (__expf(v) - 1.f);
    if (WF32) xout[(size_t)(p0 + pl) * 256 + head * 64 + f] = v;
    if (WBF) {
      // xp layout for proj<256>: node nn=p0+pl (tile=blockIdx.x), feature k=head*64+f
      size_t oi = ((((size_t)blockIdx.x * 8 + head * 2 + (f >> 5)) * 4 + ((f & 31) >> 3)) * 16 + pl) * 8 + (f & 7);
      xohi[oi] = bf16_rne(v);
    }
  }
}

// ---------------- layer-2 projection (F_out=3), 4 nodes/block, h2 stride-4 ----------------
__global__ void h3_kernel(const float* __restrict__ x, const float* __restrict__ W,
                          const float* __restrict__ a, float* __restrict__ h2,
                          float* __restrict__ s1, float* __restrict__ s2,
                          float* __restrict__ pm1h3) {
  const int n0 = blockIdx.x * 4;
  const int head = threadIdx.x >> 6, o = threadIdx.x & 63;
  __shared__ float xr[4][256];
  for (int k = threadIdx.x; k < 1024; k += 256) xr[k >> 8][k & 255] = x[(size_t)n0 * 256 + k];
  __syncthreads();
  const float* __restrict__ Wh = W + (size_t)head * 256 * 3;
  float m1 = -3.4e38f;
#pragma unroll
  for (int jj = 0; jj < 4; jj++) {
    float a0 = 0.f, a1 = 0.f, a2 = 0.f;
#pragma unroll
    for (int i = 0; i < 4; i++) {
      int k = o + 64 * i;
      float xv = xr[jj][k];
      a0 = fmaf(xv, Wh[k * 3 + 0], a0);
      a1 = fmaf(xv, Wh[k * 3 + 1], a1);
      a2 = fmaf(xv, Wh[k * 3 + 2], a2);
    }
    for (int s = 32; s; s >>= 1) {
      a0 += __shfl_xor(a0, s); a1 += __shfl_xor(a1, s); a2 += __shfl_xor(a2, s);
    }
    float p1 = (a0 * a[head * 6 + 0] + a1 * a[head * 6 + 1] + a2 * a[head * 6 + 2]) * LOG2E;
    float p2 = (a0 * a[head * 6 + 3] + a1 * a[head * 6 + 4] + a2 * a[head * 6 + 5]) * LOG2E;
    m1 = fmaxf(m1, p1);
    if (o == 0) {
      float* hq = h2 + ((size_t)head * N + n0 + jj) * 4;
      hq[0] = a0; hq[1] = a1; hq[2] = a2; hq[3] = 0.f;
      s1[head * N + n0 + jj] = p1;
      s2[head * N + n0 + jj] = p2;
    }
  }
  if (o == 0) pm1h3[head * 512 + blockIdx.x] = m1;
}

// ---------------- layer-2 aggregation, self-normalizing, fused head-mean + ELU -> emb ----------------
__global__ void agg2_kernel(const float* __restrict__ h2, const float* __restrict__ s1,
                            const float* __restrict__ s2, const float* __restrict__ pm1h3,
                            const unsigned long long* __restrict__ mask,
                            float* __restrict__ emb) {
  const int p = blockIdx.x;
  const int head = threadIdx.x >> 6, lane = threadIdx.x & 63;
  const float s2pv = s2[head * N + p];
  float sm = -3.4e38f;
  for (int i = lane; i < 512; i += 64) sm = fmaxf(sm, pm1h3[head * 512 + i]);
#pragma unroll
  for (int s = 1; s < 64; s <<= 1) sm = fmaxf(sm, __shfl_xor(sm, s));
  float mraw = sm + s2pv;
  const float mhv = fmaxf(mraw, ALPHA * mraw);
  const float c1 = s2pv - mhv;
  const float c2 = ALPHA * s2pv - mhv;
  const float* __restrict__ s1h = s1 + head * N;
  float a0 = 0.f, a1 = 0.f, a2 = 0.f, wsum = 0.f;
#pragma unroll 2
  for (int i = 0; i < 32; i++) {
    unsigned long long mwd = mask[(size_t)p * NW + i];
    int q = i * 64 + lane;
    if ((mwd >> lane) & 1ull) {
      float sv = s1h[q];
      float lr = fmaxf(sv + c1, fmaf(sv, ALPHA, c2));
      float w = exp2f(lr);
      float4 hv = *(const float4*)(h2 + ((size_t)head * N + q) * 4);
      a0 = fmaf(w, hv.x, a0);
      a1 = fmaf(w, hv.y, a1);
      a2 = fmaf(w, hv.z, a2);
      wsum += w;
    }
  }
  for (int s = 32; s; s >>= 1) {
    a0 += __shfl_xor(a0, s); a1 += __shfl_xor(a1, s);
    a2 += __shfl_xor(a2, s); wsum += __shfl_xor(wsum, s);
  }
  __shared__ float red[4][4];
  if (lane == 0) { red[head][0] = a0; red[head][1] = a1; red[head][2] = a2; red[head][3] = wsum; }
  __syncthreads();
  if (threadIdx.x < 3) {
    int f = threadIdx.x;
    float v = 0.f;
#pragma unroll
    for (int hh = 0; hh < 4; hh++) v += red[hh][f] / red[hh][3];
    v *= 0.25f;
    v = v > 0.f ? v : (__expf(v) - 1.f);
    emb[p * 3 + f] = v;
  }
}

// ---------------- all-pairs edge classifier (packed fp16 inner) ----------------
__global__ void cls_kernel(const float* __restrict__ emb,
                           const float* __restrict__ W1, const float* __restrict__ b1,
                           const float* __restrict__ W2, const float* __restrict__ b2,
                           float* __restrict__ out) {
  int q = blockIdx.x * 256 + threadIdx.x;
  int p0 = blockIdx.y * 8;
  __shared__ float ep[8][3];
  __shared__ __half2 w1h[96], b1h[32], w2h[32];
  __shared__ float b2s;
  int t = threadIdx.x;
  if (t < 96) w1h[t] = __float2half2_rn(W1[t]);
  else if (t < 128) b1h[t - 96] = __float2half2_rn(b1[t - 96]);
  else if (t < 160) w2h[t - 128] = __float2half2_rn(W2[t - 128]);
  else if (t == 160) b2s = b2[0];
  else if (t >= 192 && t < 216) ((float*)ep)[t - 192] = emb[p0 * 3 + t - 192];
  __syncthreads();
  float e0 = emb[q * 3 + 0], e1 = emb[q * 3 + 1], e2 = emb[q * 3 + 2];
  __half2 d0[4], d1[4], d2[4];
#pragma unroll
  for (int ip = 0; ip < 4; ip++) {
    d0[ip] = __floats2half2_rn(fabsf(ep[2 * ip][0] - e0), fabsf(ep[2 * ip + 1][0] - e0));
    d1[ip] = __floats2half2_rn(fabsf(ep[2 * ip][1] - e1), fabsf(ep[2 * ip + 1][1] - e1));
    d2[ip] = __floats2half2_rn(fabsf(ep[2 * ip][2] - e2), fabsf(ep[2 * ip + 1][2] - e2));
  }
  const __half2 hz = __float2half2_rn(0.f);
  __half2 acc[4] = {hz, hz, hz, hz};
#pragma unroll
  for (int j = 0; j < 32; j++) {
    __half2 c0 = w1h[j], c1 = w1h[32 + j], c2 = w1h[64 + j], bb = b1h[j], w2 = w2h[j];
#pragma unroll
    for (int ip = 0; ip < 4; ip++) {
      __half2 hv = __hfma2(d0[ip], c0, __hfma2(d1[ip], c1, __hfma2(d2[ip], c2, bb)));
      hv = relu_h2(hv);
      acc[ip] = __hfma2(hv, w2, acc[ip]);
    }
  }
#pragma unroll
  for (int ip = 0; ip < 4; ip++) {
    float x0 = __low2float(acc[ip]) + b2s;
    float x1 = __high2float(acc[ip]) + b2s;
    out[(size_t)(p0 + 2 * ip) * N + q] = 1.f / (1.f + __expf(-x0));
    out[(size_t)(p0 + 2 * ip + 1) * N + q] = 1.f / (1.f + __expf(-x1));
  }
}

extern "C" void kernel_launch(void* const* d_in, const int* in_sizes, int n_in,
                              void* d_out, int out_size, void* d_ws, size_t ws_size,
                              hipStream_t stream) {
  const float* nf    = (const float*)d_in[0];
  const int*   adj   = (const int*)d_in[1];
  const float* encW1 = (const float*)d_in[2];
  const float* encb1 = (const float*)d_in[3];
  const float* encW2 = (const float*)d_in[4];
  const float* encb2 = (const float*)d_in[5];
  const float* gatW0 = (const float*)d_in[6];
  const float* gata0 = (const float*)d_in[7];
  const float* gatW1 = (const float*)d_in[8];
  const float* gata1 = (const float*)d_in[9];
  const float* gatW2 = (const float*)d_in[10];
  const float* gata2 = (const float*)d_in[11];
  const float* clsW1 = (const float*)d_in[12];
  const float* clsb1 = (const float*)d_in[13];
  const float* clsW2 = (const float*)d_in[14];
  const float* clsb2 = (const float*)d_in[15];

  float* ws = (float*)d_ws;
  unsigned short* hT   = (unsigned short*)ws;              // 524288 sh = 262144 f
  float* s1   = ws + 262144;                               // 8192
  float* s2   = s1 + 8192;                                 // 8192
  float* pm1  = s2 + 8192;                                 // 512
  float* pm1h3= pm1 + 512;                                 // 2048
  unsigned short* x0hi = (unsigned short*)(pm1h3 + 2048);  // 65536 f
  unsigned short* wt0hi= x0hi + 131072;                    // 8192 f
  unsigned short* wt0lo= wt0hi + 16384;                    // 8192 f
  unsigned short* wt1hi= wt0lo + 16384;                    // 32768 f
  unsigned short* wt1lo= wt1hi + 65536;                    // 32768 f
  unsigned short* xAhi = wt1lo + 65536;                    // 262144 f
  float* xB   = (float*)(xAhi + 524288);                   // 524288 f
  float* h2   = xB + 524288;                               // 32768 f (stride-4)
  unsigned long long* mask = (unsigned long long*)(h2 + 32768); // 131072 f

  float* emb = (float*)d_out;
  float* eprob = emb + N * 3;

  prep_kernel<<<dim3(512), dim3(512), 0, stream>>>(
      nf, adj, encW1, encb1, encW2, encb2, gatW0, gatW1,
      mask, wt0hi, wt0lo, wt1hi, wt1lo, x0hi);

  // ---- GAT layer 0 ----
  proj_mfma_kernel<64><<<dim3(N / 16, 4), dim3(256), 0, stream>>>(
      x0hi, wt0hi, wt0lo, gata0, hT, s1, s2, pm1);
  agg_fused_kernel<false, true><<<dim3(N / 16, 4), dim3(512), 0, stream>>>(
      hT, s1, s2, pm1, mask, nullptr, xAhi);

  // ---- GAT layer 1 ----
  proj_mfma_kernel<256><<<dim3(N / 16, 4), dim3(256), 0, stream>>>(
      xAhi, wt1hi, wt1lo, gata1, hT, s1, s2, pm1);
  agg_fused_kernel<true, false><<<dim3(N / 16, 4), dim3(512), 0, stream>>>(
      hT, s1, s2, pm1, mask, xB, nullptr);

  // ---- GAT layer 2 ----
  h3_kernel<<<dim3(N / 4), dim3(256), 0, stream>>>(xB, gatW2, gata2, h2, s1, s2, pm1h3);
  agg2_kernel<<<dim3(N), dim3(256), 0, stream>>>(h2, s1, s2, pm1h3, mask, emb);

  // ---- classifier ----
  cls_kernel<<<dim3(8, N / 8), dim3(256), 0, stream>>>(emb, clsW1, clsb1, clsW2, clsb2, eprob);
}

// Round 16
// 84.426 us; speedup vs baseline: 1.0557x; 1.0077x over previous
//
#include <hip/hip_runtime.h>
#include <hip/hip_bf16.h>
#include <hip/hip_fp16.h>

#define ALPHA 0.2f
#define LOG2E 1.44269504088896340736f
constexpr int N = 2048;
constexpr int NW = N / 64;     // 32 mask words per row

typedef __attribute__((ext_vector_type(8))) short short8v;  // bf16 bits x8
typedef __attribute__((ext_vector_type(4))) float f32x4;

__device__ inline unsigned short bf16_rne(float f) {
  unsigned u = __float_as_uint(f);
  return (unsigned short)((u + 0x7fffu + ((u >> 16) & 1u)) >> 16);
}

// packed fp16 ReLU via v_pk_max_f16 (avoids __hmax2 fp16/bf16 overload ambiguity)
__device__ inline __half2 relu_h2(__half2 a) {
  unsigned ua = *(unsigned*)&a, ur;
  asm("v_pk_max_f16 %0, %1, 0" : "=v"(ur) : "v"(ua));
  return *(__half2*)&ur;
}

// ---- Fragment-packed layouts (wave-contiguous 1KB chunks; lane = kgrp*16+il) ----
// wtp[head][otile(4)][ks(K/32)][lane(64)][e(8)]   (A of proj: row o = ot*16+il, k = ks*32+(lane>>4)*8+e)
// xp  [ntile(N/16)][ks(K/32)][lane(64)][e(8)]     (B of proj: col n = nt*16+il)
// hTp [head][qchunk(N/32)][ff(4)][lane(64)][e(8)] (B of agg: f = ff*16+(lane&15), q = qc*32+(lane>>4)*8+e)

// ---------------- prep: pack adj + W transpose/split/pack + encoder ----------------
__global__ void __launch_bounds__(512) prep_kernel(
    const float* __restrict__ nf, const int* __restrict__ adj,
    const float* __restrict__ encW1, const float* __restrict__ encb1,
    const float* __restrict__ encW2, const float* __restrict__ encb2,
    const float* __restrict__ gatW0, const float* __restrict__ gatW1,
    unsigned long long* __restrict__ mask,
    unsigned short* __restrict__ wt0hi, unsigned short* __restrict__ wt0lo,
    unsigned short* __restrict__ wt1hi, unsigned short* __restrict__ wt1lo,
    unsigned short* __restrict__ x0hi) {
  const int t = threadIdx.x, b = blockIdx.x;
  {  // pack adjacency: 512 blocks x 8 waves x 16 words
    int gwave = b * 8 + (t >> 6), lane = t & 63;
#pragma unroll
    for (int i = 0; i < 16; i++) {
      int word = gwave * 16 + i;
      unsigned long long m = __ballot(adj[(size_t)word * 64 + lane] != 0);
      if (lane == 0) mask[word] = m;
    }
  }
  {  // W0/W1 packed-transpose + hi/lo split
    int gtid = b * 512 + t;
    if (gtid < 16384) {  // W0: K=64 (KS=2)
      int head = gtid >> 12, idx = gtid & 4095;
      int o = idx >> 6, k = idx & 63;
      float v = gatW0[(head * 64 + k) * 64 + o];
      unsigned short hb = bf16_rne(v);
      size_t oi = (((((size_t)head * 4 + (o >> 4)) * 2 + (k >> 5)) * 4 + ((k & 31) >> 3)) * 16 + (o & 15)) * 8 + (k & 7);
      wt0hi[oi] = hb;
      wt0lo[oi] = bf16_rne(v - __uint_as_float((unsigned)hb << 16));
    }
    if (gtid < 65536) {  // W1: K=256 (KS=8)
      int head = gtid >> 14, idx = gtid & 16383;
      int o = idx >> 8, k = idx & 255;
      float v = gatW1[((size_t)head * 256 + k) * 64 + o];
      unsigned short hb = bf16_rne(v);
      size_t oi = (((((size_t)head * 4 + (o >> 4)) * 8 + (k >> 5)) * 4 + ((k & 31) >> 3)) * 16 + (o & 15)) * 8 + (k & 7);
      wt1hi[oi] = hb;
      wt1lo[oi] = bf16_rne(v - __uint_as_float((unsigned)hb << 16));
    }
  }
  if (b < 256) {  // encoder MLP, 8 nodes/block (two 4-node halves)
    __shared__ float nfs[2][4][10], x1e[2][4][64], pred[2][4][4][64];
    const int half = t >> 8, tl = t & 255;
    const int j = tl >> 6, o = tl & 63;
    const int n0 = b * 8 + half * 4;
    if (tl < 40) nfs[half][tl / 10][tl % 10] = nf[n0 * 10 + tl];
    __syncthreads();
    float acc = encb1[o];
#pragma unroll
    for (int k = 0; k < 10; k++) acc = fmaf(nfs[half][j][k], encW1[k * 64 + o], acc);
    x1e[half][j][o] = fmaxf(acc, 0.f);
    __syncthreads();
    {
      const int kq = j;
      float pp0 = 0, pp1 = 0, pp2 = 0, pp3 = 0;
#pragma unroll
      for (int kk = 0; kk < 16; kk++) {
        int k = kq * 16 + kk;
        float wv = encW2[k * 64 + o];
        pp0 = fmaf(x1e[half][0][k], wv, pp0);
        pp1 = fmaf(x1e[half][1][k], wv, pp1);
        pp2 = fmaf(x1e[half][2][k], wv, pp2);
        pp3 = fmaf(x1e[half][3][k], wv, pp3);
      }
      pred[half][kq][0][o] = pp0; pred[half][kq][1][o] = pp1;
      pred[half][kq][2][o] = pp2; pred[half][kq][3][o] = pp3;
    }
    __syncthreads();
    float v = encb2[o] + pred[half][0][j][o] + pred[half][1][j][o] +
              pred[half][2][j][o] + pred[half][3][j][o];
    const int n = n0 + j;  // node; feature k = o; K=64 -> KS=2
    size_t oi = ((((size_t)(n >> 4) * 2 + (o >> 5)) * 4 + ((o & 31) >> 3)) * 16 + (n & 15)) * 8 + (o & 7);
    x0hi[oi] = bf16_rne(v);
  }
}

// ---------------- MFMA projection (fragment-packed operands, 2-term hi/lo) ----------------
// grid (N/16, H), block 256 = 4 waves; wave = o-strip. Writes hTp + s1/s2 (log2e) + pm1.
template <int K>
__global__ void __launch_bounds__(256, 4)
proj_mfma_kernel(const unsigned short* __restrict__ xhi,
                 const unsigned short* __restrict__ wthi, const unsigned short* __restrict__ wtlo,
                 const float* __restrict__ avec,
                 unsigned short* __restrict__ hT, float* __restrict__ s1, float* __restrict__ s2,
                 float* __restrict__ pm1) {
  constexpr int KS = K / 32;
  const int head = blockIdx.y;
  const int n0 = blockIdx.x * 16;
  const int wave = threadIdx.x >> 6, lane = threadIdx.x & 63;
  const int il = lane & 15, kgrp = lane >> 4;
  const int o0 = wave * 16;
  const unsigned short* __restrict__ Ah = wthi + ((size_t)(head * 4 + wave) * KS) * 512 + lane * 8;
  const unsigned short* __restrict__ Al = wtlo + ((size_t)(head * 4 + wave) * KS) * 512 + lane * 8;
  const unsigned short* __restrict__ Bh = xhi + ((size_t)blockIdx.x * KS) * 512 + lane * 8;
  f32x4 acc = {0, 0, 0, 0};
#pragma unroll
  for (int ks = 0; ks < KS; ks++) {
    short8v ah = *(const short8v*)(Ah + ks * 512);
    short8v al = *(const short8v*)(Al + ks * 512);
    short8v bh = *(const short8v*)(Bh + ks * 512);
    acc = __builtin_amdgcn_mfma_f32_16x16x32_bf16(ah, bh, acc, 0, 0, 0);
    acc = __builtin_amdgcn_mfma_f32_16x16x32_bf16(al, bh, acc, 0, 0, 0);
  }
  // D: o = o0 + kgrp*4 + r (row), n = n0 + il (col). Write hTp layout.
  const int n = n0 + il;
  const size_t cbase = (((size_t)head * (N / 32) + (n >> 5)) * 4 + wave) * 512;
  const int sub = ((n & 31) >> 3) * 16;  // kgrp_agg*16
  const int eoff = n & 7;
  float p1 = 0.f, p2 = 0.f;
#pragma unroll
  for (int r = 0; r < 4; r++) {
    const int o = o0 + kgrp * 4 + r;
    hT[cbase + (size_t)(sub + kgrp * 4 + r) * 8 + eoff] = bf16_rne(acc[r]);
    p1 = fmaf(acc[r], avec[head * 128 + o], p1);
    p2 = fmaf(acc[r], avec[head * 128 + 64 + o], p2);
  }
  p1 += __shfl_xor(p1, 16); p1 += __shfl_xor(p1, 32);
  p2 += __shfl_xor(p2, 16); p2 += __shfl_xor(p2, 32);
  __shared__ float s1p[4][16], s2p[4][16];
  if (kgrp == 0) { s1p[wave][il] = p1; s2p[wave][il] = p2; }
  __syncthreads();
  if (threadIdx.x < 16) {
    int nn = n0 + threadIdx.x;
    float v1 = (s1p[0][threadIdx.x] + s1p[1][threadIdx.x] + s1p[2][threadIdx.x] + s1p[3][threadIdx.x]) * LOG2E;
    float v2 = (s2p[0][threadIdx.x] + s2p[1][threadIdx.x] + s2p[2][threadIdx.x] + s2p[3][threadIdx.x]) * LOG2E;
    s1[head * N + nn] = v1;
    s2[head * N + nn] = v2;
    float m1 = v1;
#pragma unroll
    for (int s = 1; s < 16; s <<= 1) m1 = fmaxf(m1, __shfl_xor(m1, s));
    if (threadIdx.x == 0) pm1[head * 128 + blockIdx.x] = m1;
  }
}

// ---------------- fused MFMA aggregation + denom + normalize + ELU + concat ----------------
// grid (N/16, H), block 512 = 8 waves; wave w = K-chunk of 256 q. Single-MFMA, packed B.
// VALU-trimmed: lrelu-sub fold (c1/c2) + v_cvt_pk_bf16_f32 packing.
template <bool WF32, bool WBF>
__global__ void __launch_bounds__(512, 4)
agg_fused_kernel(const unsigned short* __restrict__ hTu,
                 const float* __restrict__ s1, const float* __restrict__ s2,
                 const float* __restrict__ pm1,
                 const unsigned long long* __restrict__ mask,
                 float* __restrict__ xout, unsigned short* __restrict__ xohi) {
  const int head = blockIdx.y;
  const int p0 = blockIdx.x * 16;
  const int wave = threadIdx.x >> 6, lane = threadIdx.x & 63;
  const int col = lane & 15, kgrp = lane >> 4;
  const int p = p0 + col;
  const float s2pv = s2[head * N + p];
  float sm = fmaxf(pm1[head * 128 + lane], pm1[head * 128 + 64 + lane]);
#pragma unroll
  for (int s = 1; s < 64; s <<= 1) sm = fmaxf(sm, __shfl_xor(sm, s));
  const float mraw = sm + s2pv;
  const float mp = fmaxf(mraw, ALPHA * mraw);
  // fold: lrelu(sv+s2p) - mp = max(sv + c1, ALPHA*sv + c2)
  const float c1 = s2pv - mp;
  const float c2 = ALPHA * s2pv - mp;
  const float* __restrict__ s1h = s1 + head * N;
  const int qbase = wave * 256;
  const unsigned long long* __restrict__ mr = mask + (size_t)p * NW + (qbase >> 6);
  unsigned long long mw0 = mr[0], mw1 = mr[1], mw2 = mr[2], mw3 = mr[3];
  const unsigned short* __restrict__ bbase =
      hTu + (((size_t)head * (N / 32) + wave * 8) * 4) * 512 + lane * 8;

  f32x4 acc[4] = {{0,0,0,0},{0,0,0,0},{0,0,0,0},{0,0,0,0}};
  float wsum = 0.f;
#pragma unroll
  for (int ks = 0; ks < 8; ks++) {
    const int qa = qbase + ks * 32 + kgrp * 8;
    float4 s1v0 = *(const float4*)(s1h + qa);
    float4 s1v1 = *(const float4*)(s1h + qa + 4);
    unsigned long long mwsel = (ks < 2) ? mw0 : (ks < 4) ? mw1 : (ks < 6) ? mw2 : mw3;
    unsigned b8 = (unsigned)((mwsel >> ((ks & 1) * 32 + kgrp * 8)) & 0xFFull);
    float sv[8] = {s1v0.x, s1v0.y, s1v0.z, s1v0.w, s1v1.x, s1v1.y, s1v1.z, s1v1.w};
    float w[8];
#pragma unroll
    for (int e = 0; e < 8; e++) {
      float lr = fmaxf(sv[e] + c1, fmaf(sv[e], ALPHA, c2));
      float ww = exp2f(lr);
      ww = ((b8 >> e) & 1u) ? ww : 0.f;
      wsum += ww;
      w[e] = ww;
    }
    union { short8v s; unsigned u[4]; } av;
#pragma unroll
    for (int e2 = 0; e2 < 4; e2++)
      asm("v_cvt_pk_bf16_f32 %0, %1, %2" : "=v"(av.u[e2]) : "v"(w[2 * e2]), "v"(w[2 * e2 + 1]));
#pragma unroll
    for (int ff = 0; ff < 4; ff++) {
      short8v b_hi = *(const short8v*)(bbase + ((size_t)ks * 4 + ff) * 512);
      acc[ff] = __builtin_amdgcn_mfma_f32_16x16x32_bf16(av.s, b_hi, acc[ff], 0, 0, 0);
    }
  }
  wsum += __shfl_xor(wsum, 16);
  wsum += __shfl_xor(wsum, 32);

  __shared__ float red[8][16][65];
  __shared__ float wred[8][16];
#pragma unroll
  for (int ff = 0; ff < 4; ff++)
#pragma unroll
    for (int r = 0; r < 4; r++)
      red[wave][kgrp * 4 + r][ff * 16 + col] = acc[ff][r];
  if (lane < 16) wred[wave][lane] = wsum;
  __syncthreads();
#pragma unroll
  for (int rep = 0; rep < 2; rep++) {
    int idx = threadIdx.x + rep * 512;
    int pl = idx >> 6, f = idx & 63;
    float num = 0.f, dn = 0.f;
#pragma unroll
    for (int w8 = 0; w8 < 8; w8++) { num += red[w8][pl][f]; dn += wred[w8][pl]; }
    float v = num / dn;
    v = v > 0.f ? v : (__expf(v) - 1.f);
    if (WF32) xout[(size_t)(p0 + pl) * 256 + head * 64 + f] = v;
    if (WBF) {
      // xp layout for proj<256>: node nn=p0+pl (tile=blockIdx.x), feature k=head*64+f
      size_t oi = ((((size_t)blockIdx.x * 8 + head * 2 + (f >> 5)) * 4 + ((f & 31) >> 3)) * 16 + pl) * 8 + (f & 7);
      xohi[oi] = bf16_rne(v);
    }
  }
}

// ---------------- layer-2 projection (F_out=3), 4 nodes/block, h2 stride-4 ----------------
__global__ void h3_kernel(const float* __restrict__ x, const float* __restrict__ W,
                          const float* __restrict__ a, float* __restrict__ h2,
                          float* __restrict__ s1, float* __restrict__ s2,
                          float* __restrict__ pm1h3) {
  const int n0 = blockIdx.x * 4;
  const int head = threadIdx.x >> 6, o = threadIdx.x & 63;
  __shared__ float xr[4][256];
  for (int k = threadIdx.x; k < 1024; k += 256) xr[k >> 8][k & 255] = x[(size_t)n0 * 256 + k];
  __syncthreads();
  const float* __restrict__ Wh = W + (size_t)head * 256 * 3;
  float m1 = -3.4e38f;
#pragma unroll
  for (int jj = 0; jj < 4; jj++) {
    float a0 = 0.f, a1 = 0.f, a2 = 0.f;
#pragma unroll
    for (int i = 0; i < 4; i++) {
      int k = o + 64 * i;
      float xv = xr[jj][k];
      a0 = fmaf(xv, Wh[k * 3 + 0], a0);
      a1 = fmaf(xv, Wh[k * 3 + 1], a1);
      a2 = fmaf(xv, Wh[k * 3 + 2], a2);
    }
    for (int s = 32; s; s >>= 1) {
      a0 += __shfl_xor(a0, s); a1 += __shfl_xor(a1, s); a2 += __shfl_xor(a2, s);
    }
    float p1 = (a0 * a[head * 6 + 0] + a1 * a[head * 6 + 1] + a2 * a[head * 6 + 2]) * LOG2E;
    float p2 = (a0 * a[head * 6 + 3] + a1 * a[head * 6 + 4] + a2 * a[head * 6 + 5]) * LOG2E;
    m1 = fmaxf(m1, p1);
    if (o == 0) {
      float* hq = h2 + ((size_t)head * N + n0 + jj) * 4;
      hq[0] = a0; hq[1] = a1; hq[2] = a2; hq[3] = 0.f;
      s1[head * N + n0 + jj] = p1;
      s2[head * N + n0 + jj] = p2;
    }
  }
  if (o == 0) pm1h3[head * 512 + blockIdx.x] = m1;
}

// ---------------- layer-2 aggregation, self-normalizing, fused head-mean + ELU -> emb ----------------
__global__ void agg2_kernel(const float* __restrict__ h2, const float* __restrict__ s1,
                            const float* __restrict__ s2, const float* __restrict__ pm1h3,
                            const unsigned long long* __restrict__ mask,
                            float* __restrict__ emb) {
  const int p = blockIdx.x;
  const int head = threadIdx.x >> 6, lane = threadIdx.x & 63;
  const float s2pv = s2[head * N + p];
  float sm = -3.4e38f;
  for (int i = lane; i < 512; i += 64) sm = fmaxf(sm, pm1h3[head * 512 + i]);
#pragma unroll
  for (int s = 1; s < 64; s <<= 1) sm = fmaxf(sm, __shfl_xor(sm, s));
  float mraw = sm + s2pv;
  const float mhv = fmaxf(mraw, ALPHA * mraw);
  const float c1 = s2pv - mhv;
  const float c2 = ALPHA * s2pv - mhv;
  const float* __restrict__ s1h = s1 + head * N;
  float a0 = 0.f, a1 = 0.f, a2 = 0.f, wsum = 0.f;
#pragma unroll 2
  for (int i = 0; i < 32; i++) {
    unsigned long long mwd = mask[(size_t)p * NW + i];
    int q = i * 64 + lane;
    if ((mwd >> lane) & 1ull) {
      float sv = s1h[q];
      float lr = fmaxf(sv + c1, fmaf(sv, ALPHA, c2));
      float w = exp2f(lr);
      float4 hv = *(const float4*)(h2 + ((size_t)head * N + q) * 4);
      a0 = fmaf(w, hv.x, a0);
      a1 = fmaf(w, hv.y, a1);
      a2 = fmaf(w, hv.z, a2);
      wsum += w;
    }
  }
  for (int s = 32; s; s >>= 1) {
    a0 += __shfl_xor(a0, s); a1 += __shfl_xor(a1, s);
    a2 += __shfl_xor(a2, s); wsum += __shfl_xor(wsum, s);
  }
  __shared__ float red[4][4];
  if (lane == 0) { red[head][0] = a0; red[head][1] = a1; red[head][2] = a2; red[head][3] = wsum; }
  __syncthreads();
  if (threadIdx.x < 3) {
    int f = threadIdx.x;
    float v = 0.f;
#pragma unroll
    for (int hh = 0; hh < 4; hh++) v += red[hh][f] / red[hh][3];
    v *= 0.25f;
    v = v > 0.f ? v : (__expf(v) - 1.f);
    emb[p * 3 + f] = v;
  }
}

// ---------------- all-pairs edge classifier: symmetric upper-triangle tiles + mirror ----------------
// edge_probs[p][q] == edge_probs[q][p] exactly (|emb_p-emb_q| symmetric).
// grid = 528 triangular 64x64 tiles; block 256 (thread = q-in-tile x 4 p-groups of 16).
__global__ void __launch_bounds__(256) cls_kernel(
    const float* __restrict__ emb,
    const float* __restrict__ W1, const float* __restrict__ b1,
    const float* __restrict__ W2, const float* __restrict__ b2,
    float* __restrict__ out) {
  // map blockIdx.x -> (pi, qi), pi <= qi, 32x32 tile grid
  int bb = blockIdx.x;
  int pi = 0, cum = 0;
  while (cum + (32 - pi) <= bb) { cum += 32 - pi; pi++; }
  const int qi = pi + (bb - cum);
  const int P0 = pi * 64, Q0 = qi * 64;
  const int t = threadIdx.x;
  __shared__ __half2 w1h[96], b1h[32], w2h[32];
  __shared__ float b2s;
  __shared__ float epl[64][3];   // p-tile embeddings
  __shared__ float eql[64][3];   // q-tile embeddings
  __shared__ float stile[64][65];  // [p][q] tile of probs (pad-65)
  if (t < 96) w1h[t] = __float2half2_rn(W1[t]);
  else if (t < 128) b1h[t - 96] = __float2half2_rn(b1[t - 96]);
  else if (t < 160) w2h[t - 128] = __float2half2_rn(W2[t - 128]);
  else if (t == 160) b2s = b2[0];
  if (t < 192) ((float*)epl)[t] = emb[P0 * 3 + t];
  else if (t < 224) { int i = t - 192; ((float*)eql)[i] = emb[Q0 * 3 + i]; }
  __syncthreads();
  if (t < 160) ((float*)eql)[t + 32] = emb[Q0 * 3 + 32 + t];
  __syncthreads();

  const int tq = t & 63, pg = t >> 6;  // q within tile; p-group (16 rows each)
  const int pb = pg * 16;
  const float e0 = eql[tq][0], e1 = eql[tq][1], e2 = eql[tq][2];
  __half2 d0[8], d1[8], d2[8];
#pragma unroll
  for (int ip = 0; ip < 8; ip++) {
    d0[ip] = __floats2half2_rn(fabsf(epl[pb + 2 * ip][0] - e0), fabsf(epl[pb + 2 * ip + 1][0] - e0));
    d1[ip] = __floats2half2_rn(fabsf(epl[pb + 2 * ip][1] - e1), fabsf(epl[pb + 2 * ip + 1][1] - e1));
    d2[ip] = __floats2half2_rn(fabsf(epl[pb + 2 * ip][2] - e2), fabsf(epl[pb + 2 * ip + 1][2] - e2));
  }
  const __half2 hz = __float2half2_rn(0.f);
  __half2 acc[8] = {hz, hz, hz, hz, hz, hz, hz, hz};
#pragma unroll
  for (int j = 0; j < 32; j++) {
    __half2 c0 = w1h[j], c1 = w1h[32 + j], c2 = w1h[64 + j], bbv = b1h[j], w2 = w2h[j];
#pragma unroll
    for (int ip = 0; ip < 8; ip++) {
      __half2 hv = __hfma2(d0[ip], c0, __hfma2(d1[ip], c1, __hfma2(d2[ip], c2, bbv)));
      hv = relu_h2(hv);
      acc[ip] = __hfma2(hv, w2, acc[ip]);
    }
  }
#pragma unroll
  for (int ip = 0; ip < 8; ip++) {
    float x0 = __low2float(acc[ip]) + b2s;
    float x1 = __high2float(acc[ip]) + b2s;
    stile[pb + 2 * ip][tq] = 1.f / (1.f + __expf(-x0));
    stile[pb + 2 * ip + 1][tq] = 1.f / (1.f + __expf(-x1));
  }
  __syncthreads();
  // direct write: out[P0+pl][Q0+qq]
#pragma unroll
  for (int pass = 0; pass < 16; pass++) {
    int idx = t + pass * 256;
    int pl = idx >> 6, qq = idx & 63;
    out[(size_t)(P0 + pl) * N + Q0 + qq] = stile[pl][qq];
  }
  // mirror write: out[Q0+ql][P0+pc] = stile[pc][ql]
  if (pi != qi) {
#pragma unroll
    for (int pass = 0; pass < 16; pass++) {
      int idx = t + pass * 256;
      int ql = idx >> 6, pc = idx & 63;
      out[(size_t)(Q0 + ql) * N + P0 + pc] = stile[pc][ql];
    }
  }
}

extern "C" void kernel_launch(void* const* d_in, const int* in_sizes, int n_in,
                              void* d_out, int out_size, void* d_ws, size_t ws_size,
                              hipStream_t stream) {
  const float* nf    = (const float*)d_in[0];
  const int*   adj   = (const int*)d_in[1];
  const float* encW1 = (const float*)d_in[2];
  const float* encb1 = (const float*)d_in[3];
  const float* encW2 = (const float*)d_in[4];
  const float* encb2 = (const float*)d_in[5];
  const float* gatW0 = (const float*)d_in[6];
  const float* gata0 = (const float*)d_in[7];
  const float* gatW1 = (const float*)d_in[8];
  const float* gata1 = (const float*)d_in[9];
  const float* gatW2 = (const float*)d_in[10];
  const float* gata2 = (const float*)d_in[11];
  const float* clsW1 = (const float*)d_in[12];
  const float* clsb1 = (const float*)d_in[13];
  const float* clsW2 = (const float*)d_in[14];
  const float* clsb2 = (const float*)d_in[15];

  float* ws = (float*)d_ws;
  unsigned short* hT   = (unsigned short*)ws;              // 524288 sh = 262144 f
  float* s1   = ws + 262144;                               // 8192
  float* s2   = s1 + 8192;                                 // 8192
  float* pm1  = s2 + 8192;                                 // 512
  float* pm1h3= pm1 + 512;                                 // 2048
  unsigned short* x0hi = (unsigned short*)(pm1h3 + 2048);  // 65536 f
  unsigned short* wt0hi= x0hi + 131072;                    // 8192 f
  unsigned short* wt0lo= wt0hi + 16384;                    // 8192 f
  unsigned short* wt1hi= wt0lo + 16384;                    // 32768 f
  unsigned short* wt1lo= wt1hi + 65536;                    // 32768 f
  unsigned short* xAhi = wt1lo + 65536;                    // 262144 f
  float* xB   = (float*)(xAhi + 524288);                   // 524288 f
  float* h2   = xB + 524288;                               // 32768 f (stride-4)
  unsigned long long* mask = (unsigned long long*)(h2 + 32768); // 131072 f

  float* emb = (float*)d_out;
  float* eprob = emb + N * 3;

  prep_kernel<<<dim3(512), dim3(512), 0, stream>>>(
      nf, adj, encW1, encb1, encW2, encb2, gatW0, gatW1,
      mask, wt0hi, wt0lo, wt1hi, wt1lo, x0hi);

  // ---- GAT layer 0 ----
  proj_mfma_kernel<64><<<dim3(N / 16, 4), dim3(256), 0, stream>>>(
      x0hi, wt0hi, wt0lo, gata0, hT, s1, s2, pm1);
  agg_fused_kernel<false, true><<<dim3(N / 16, 4), dim3(512), 0, stream>>>(
      hT, s1, s2, pm1, mask, nullptr, xAhi);

  // ---- GAT layer 1 ----
  proj_mfma_kernel<256><<<dim3(N / 16, 4), dim3(256), 0, stream>>>(
      xAhi, wt1hi, wt1lo, gata1, hT, s1, s2, pm1);
  agg_fused_kernel<true, false><<<dim3(N / 16, 4), dim3(512), 0, stream>>>(
      hT, s1, s2, pm1, mask, xB, nullptr);

  // ---- GAT layer 2 ----
  h3_kernel<<<dim3(N / 4), dim3(256), 0, stream>>>(xB, gatW2, gata2, h2, s1, s2, pm1h3);
  agg2_kernel<<<dim3(N), dim3(256), 0, stream>>>(h2, s1, s2, pm1h3, mask, emb);

  // ---- classifier (symmetric, 528 triangular tiles) ----
  cls_kernel<<<dim3(528), dim3(256), 0, stream>>>(emb, clsW1, clsb1, clsW2, clsb2, eprob);
}